// Round 6
// baseline (216.781 us; speedup 1.0000x reference)
//
#include <hip/hip_runtime.h>

// DISCO S2 conv, equiangular 360x720 -> 180x360, K=3, B*C=128.
// out[bc, k*180+t, p] = sum_{e in seg(k,t)} val[e]*qw[lat[e]] * x[bc, lat[e], (lon[e]-2p-2) mod 720]
//
// Round-6: minimal hot loop.
//  - meta expanded per wave-id: mw[wid][e] = { lds_byte_off, cf }. Lane order
//    reversed (p = wid*64+63-lane) and each LDS row has a 64-slot wrap mirror
//    (424 slots), so per-lane slot = base + lane: NO mod, NO decode in loop.
//    Hot loop: s_load(uniform) + v_add + ds_read_b128 + 4 v_fmac.
//  - grid (bcg, t, k) one segment/block; pole-first t order; full-row collapse
//    for constant-val rows (exact poles) via shuffle-reduce.
//  - LDS 40.8 KB -> 3 blocks/CU.

#define NLAT_IN  360
#define NLON_IN  720
#define NLAT_OUT 180
#define NLON_OUT 360
#define KSIZE    3
#define NSEG     (KSIZE * NLAT_OUT)    // 540
#define CHW      (NLAT_IN * NLON_IN)   // 259200
#define BCTOT    128
#define G        4
#define NBCG     (BCTOT / G)           // 32
#define MAXR     3
#define PH       10
#define NTHREADS 384
#define NWAVES   (NTHREADS / 64)
#define SLOTS    424                   // 360 + 64 wrap mirror
#define ROWB     (SLOTS * 16)          // 6784 B per row-parity plane

// ---------------- prep ----------------

// per (s,j): ptrh, hbase/hlast, flags — all from local binary searches.
__global__ void prep1_kernel(const int* __restrict__ seg, const int* __restrict__ lat,
                             const float* __restrict__ val, int nnz,
                             int* __restrict__ ptrh, int* __restrict__ hbase,
                             int* __restrict__ hlast, int* __restrict__ flags) {
    int idx = blockIdx.x * blockDim.x + threadIdx.x;
    if (idx >= NSEG * PH) return;
    int s = idx / PH, j = idx - s * PH;
    int lo = 0, hi = nnz;
    while (lo < hi) { int m = (lo + hi) >> 1; if (seg[m] < s) lo = m + 1; else hi = m; }
    int e0 = lo;
    lo = e0; hi = nnz;
    while (lo < hi) { int m = (lo + hi) >> 1; if (seg[m] < s + 1) lo = m + 1; else hi = m; }
    int e1 = lo;
    if (e0 >= e1) {
        ptrh[idx] = e0; flags[idx] = 0;
        if (j == 0) { hbase[s] = 1 << 28; hlast[s] = -(1 << 28); }
        return;
    }
    int hb = lat[e0];
    if (j == 0) { hbase[s] = hb; hlast[s] = lat[e1 - 1]; }
    int a;
    { int tg = hb + j; lo = e0; hi = e1;
      while (lo < hi) { int m = (lo + hi) >> 1; if (lat[m] < tg) lo = m + 1; else hi = m; }
      a = lo; }
    ptrh[idx] = a;
    int f = 0;
    if (j < PH - 1) {
        int tg = hb + j + 1; lo = a; hi = e1;
        while (lo < hi) { int m = (lo + hi) >> 1; if (lat[m] < tg) lo = m + 1; else hi = m; }
        int b = lo;
        if (b - a == NLON_IN) {
            float v0 = val[a], v1 = val[a + 240], v2 = val[a + 480];
            float d = fmaxf(fabsf(v0 - v1), fmaxf(fabsf(v0 - v2), fabsf(v1 - v2)));
            f = (d < 1e-5f) ? 1 : 0;
        }
    }
    flags[idx] = f;
}

// mw[wid][e] = { rp*ROWB + b0*16, val*qw } with b0 = (s0 - 64*wid - 63) mod 360.
__global__ void prep2_kernel(const int* __restrict__ seg, const int* __restrict__ lat,
                             const int* __restrict__ lon, const float* __restrict__ val,
                             const float* __restrict__ qw, const int* __restrict__ hbase,
                             int nnz, uint2* __restrict__ mw) {
    int e = blockIdx.x * blockDim.x + threadIdx.x;
    if (e >= nnz) return;
    int wid = blockIdx.y;
    int w = lon[e], h = lat[e];
    int i0 = w >> 1;
    int s0 = i0 ? (i0 - 1) : (NLON_OUT - 1);
    int rp = ((h - hbase[seg[e]]) % MAXR) * 2 + (w & 1);
    int b0 = s0 + 720 - 63 - 64 * wid;
    if (b0 >= 720) b0 -= 720;
    if (b0 >= 360) b0 -= 360;
    mw[(size_t)wid * nnz + e] =
        make_uint2((unsigned)(rp * ROWB + (b0 << 4)), __float_as_uint(val[e] * qw[h]));
}

// ---------------- main ----------------

__global__ __launch_bounds__(NTHREADS) void disco_kernel(
    const float* __restrict__ x,
    const uint2* __restrict__ mw,
    const int*   __restrict__ ptrh,
    const int*   __restrict__ hbase,
    const int*   __restrict__ hlast,
    const int*   __restrict__ flags,
    int nnz,
    float*       __restrict__ out)
{
    __shared__ float4 ldsx[MAXR * 2][SLOTS];      // 40,704 B -> 3 blocks/CU
    __shared__ float4 rsum_lds[MAXR];
    __shared__ float4 wred[NWAVES];

    const int tid  = threadIdx.x;
    const int lane = tid & 63, wid = tid >> 6;
    const int p    = wid * 64 + 63 - lane;        // reversed lane -> ascending slots
    const int bc0  = blockIdx.x * G;
    const int ty   = blockIdx.y;
    const int t    = (ty & 1) ? (NLAT_OUT - 1 - (ty >> 1)) : (ty >> 1);  // poles first
    const int s    = blockIdx.z * NLAT_OUT + t;

    const int hb = hbase[s], hl = hlast[s];       // empty: hb > hl
    const uint2* mwp   = mw + (size_t)wid * nnz;  // wave-uniform base
    const char*  lbase = (const char*)&ldsx[0][0];
    const int    loff  = lane << 4;

    float a0 = 0.f, a1 = 0.f, a2 = 0.f, a3 = 0.f;

    for (int r0 = hb; r0 <= hl; r0 += MAXR) {
        const int rn = min(MAXR, hl - r0 + 1);
        __syncthreads();                           // prior window readers done
        // ---- stage rows, parity-split, with 64-col wrap mirror ----
        if (tid < NLON_OUT) {
            for (int r = 0; r < rn; ++r) {
                const float* xr = x + (size_t)bc0 * CHW + (size_t)(r0 + r) * NLON_IN + 2 * tid;
                const float2 v0 = *(const float2*)(xr);
                const float2 v1 = *(const float2*)(xr + CHW);
                const float2 v2 = *(const float2*)(xr + 2 * CHW);
                const float2 v3 = *(const float2*)(xr + 3 * CHW);
                const float4 ev = make_float4(v0.x, v1.x, v2.x, v3.x);
                const float4 ov = make_float4(v0.y, v1.y, v2.y, v3.y);
                ldsx[2 * r + 0][tid] = ev;
                ldsx[2 * r + 1][tid] = ov;
                if (tid < SLOTS - NLON_OUT) {      // mirror cols 0..63
                    ldsx[2 * r + 0][NLON_OUT + tid] = ev;
                    ldsx[2 * r + 1][NLON_OUT + tid] = ov;
                }
            }
        }
        __syncthreads();
        // ---- rows of this window ----
        for (int r = 0; r < rn; ++r) {
            const int j = (r0 + r) - hb;
            if (j < 0 || j >= PH - 1) continue;
            const int a = ptrh[s * PH + j], b = ptrh[s * PH + j + 1];
            if (a >= b) continue;                  // uniform
            if (flags[s * PH + j]) {               // constant-val full row -> cf*rowsum
                float4 v = make_float4(0.f, 0.f, 0.f, 0.f);
                if (tid < NLON_OUT) {
                    const float4 u0 = ldsx[2 * r][tid], u1 = ldsx[2 * r + 1][tid];
                    v = make_float4(u0.x + u1.x, u0.y + u1.y, u0.z + u1.z, u0.w + u1.w);
                }
#pragma unroll
                for (int off = 32; off >= 1; off >>= 1) {
                    v.x += __shfl_down(v.x, off);
                    v.y += __shfl_down(v.y, off);
                    v.z += __shfl_down(v.z, off);
                    v.w += __shfl_down(v.w, off);
                }
                if (lane == 0) wred[wid] = v;
                __syncthreads();
                if (wid == 0) {
                    float4 u = (lane < NWAVES) ? wred[lane] : make_float4(0.f, 0.f, 0.f, 0.f);
#pragma unroll
                    for (int off = 4; off >= 1; off >>= 1) {
                        u.x += __shfl_down(u.x, off);
                        u.y += __shfl_down(u.y, off);
                        u.z += __shfl_down(u.z, off);
                        u.w += __shfl_down(u.w, off);
                    }
                    if (lane == 0) rsum_lds[r] = u;
                }
                __syncthreads();
                const float  cf = __uint_as_float(mwp[a].y);
                const float4 rs = rsum_lds[r];
                a0 = fmaf(cf, rs.x, a0);
                a1 = fmaf(cf, rs.y, a1);
                a2 = fmaf(cf, rs.z, a2);
                a3 = fmaf(cf, rs.w, a3);
                continue;
            }
            // ---- hot loop: s_load meta + v_add + ds_read_b128 + 4 v_fmac ----
#pragma unroll 4
            for (int e = a; e < b; ++e) {
                const uint2  m  = mwp[e];          // wave-uniform -> SGPR
                const float4 xv = *(const float4*)(lbase + m.x + loff);
                const float  cf = __uint_as_float(m.y);
                a0 = fmaf(cf, xv.x, a0);
                a1 = fmaf(cf, xv.y, a1);
                a2 = fmaf(cf, xv.z, a2);
                a3 = fmaf(cf, xv.w, a3);
            }
        }
    }

    if (p < NLON_OUT) {
        const size_t ob = ((size_t)bc0 * NSEG + s) * NLON_OUT + p;
        out[ob]                               = a0;
        out[ob + (size_t)NSEG * NLON_OUT]     = a1;
        out[ob + (size_t)2 * NSEG * NLON_OUT] = a2;
        out[ob + (size_t)3 * NSEG * NLON_OUT] = a3;
    }
}

// ---------------- fallback (tiny ws) ----------------

__global__ void segptr_kernel(const int* __restrict__ seg, int nnz, int* __restrict__ ptr) {
    int s = blockIdx.x * blockDim.x + threadIdx.x;
    if (s > NSEG) return;
    if (s == NSEG) { ptr[NSEG] = nnz; return; }
    int lo = 0, hi = nnz;
    while (lo < hi) { int m = (lo + hi) >> 1; if (seg[m] < s) lo = m + 1; else hi = m; }
    ptr[s] = lo;
}

__global__ __launch_bounds__(384) void disco_simple_kernel(
    const float* __restrict__ x, const float* __restrict__ qw,
    const int* __restrict__ lat, const int* __restrict__ lon,
    const float* __restrict__ val, const int* __restrict__ ptr,
    float* __restrict__ out)
{
    const int p = threadIdx.x;
    if (p >= NLON_OUT) return;
    const int kt = blockIdx.x, bc0 = blockIdx.y * 8;
    const int e0 = ptr[kt], e1 = ptr[kt + 1];
    float acc[8];
#pragma unroll
    for (int g = 0; g < 8; ++g) acc[g] = 0.0f;
    const int pw = 2 * p + 2;
    const float* xb = x + (size_t)bc0 * CHW;
    for (int e = e0; e < e1; ++e) {
        const int h = lat[e], w = lon[e];
        const float cf = val[e] * qw[h];
        int col = w - pw; if (col < 0) col += NLON_IN;
        const float* src = xb + h * NLON_IN + col;
#pragma unroll
        for (int g = 0; g < 8; ++g) acc[g] = fmaf(cf, src[(size_t)g * CHW], acc[g]);
    }
    const size_t ob = ((size_t)bc0 * NSEG + kt) * NLON_OUT + p;
#pragma unroll
    for (int g = 0; g < 8; ++g) out[ob + (size_t)g * NSEG * NLON_OUT] = acc[g];
}

// ---------------- launcher ----------------

extern "C" void kernel_launch(void* const* d_in, const int* in_sizes, int n_in,
                              void* d_out, int out_size, void* d_ws, size_t ws_size,
                              hipStream_t stream)
{
    const float* x   = (const float*)d_in[0];   // [2,64,360,720] f32
    const float* qw  = (const float*)d_in[1];   // [360,1] f32
    const int*   seg = (const int*)  d_in[2];   // [nnz] i32 sorted asc
    const int*   lat = (const int*)  d_in[3];
    const int*   lon = (const int*)  d_in[4];
    const float* val = (const float*)d_in[5];
    const int    nnz = in_sizes[2];

    char* w = (char*)d_ws;
    int*   ptrh  = (int*)w;                      size_t off = (size_t)NSEG * PH * 4;   // 21600
    int*   hbase = (int*)(w + off);              off += NSEG * 4;
    int*   hlast = (int*)(w + off);              off += NSEG * 4;
    int*   flags = (int*)(w + off);              off += (size_t)NSEG * PH * 4;
    off = (off + 15) & ~(size_t)15;
    uint2* mw    = (uint2*)(w + off);            off += (size_t)NWAVES * nnz * 8;

    if (ws_size < off) {                         // tiny ws: slow-but-correct path
        int* ptr = (int*)d_ws;                   // 541 ints
        segptr_kernel<<<(NSEG + 1 + 255) / 256, 256, 0, stream>>>(seg, nnz, ptr);
        dim3 grid(NSEG, BCTOT / 8);
        disco_simple_kernel<<<grid, 384, 0, stream>>>(x, qw, lat, lon, val, ptr,
                                                      (float*)d_out);
        return;
    }

    prep1_kernel<<<(NSEG * PH + 255) / 256, 256, 0, stream>>>(seg, lat, val, nnz,
                                                              ptrh, hbase, hlast, flags);
    dim3 pgrid((nnz + 255) / 256, NWAVES);
    prep2_kernel<<<pgrid, 256, 0, stream>>>(seg, lat, lon, val, qw, hbase, nnz, mw);

    dim3 grid(NBCG, NLAT_OUT, KSIZE);
    disco_kernel<<<grid, NTHREADS, 0, stream>>>(x, mw, ptrh, hbase, hlast, flags,
                                                nnz, (float*)d_out);
}